// Round 2
// baseline (524.410 us; speedup 1.0000x reference)
//
#include <hip/hip_runtime.h>

typedef float  f32x16 __attribute__((ext_vector_type(16)));
typedef float  f32x4  __attribute__((ext_vector_type(4)));
typedef float  f32x4a __attribute__((ext_vector_type(4), aligned(4)));
typedef __bf16 bf16x8 __attribute__((ext_vector_type(8)));
typedef short  short8 __attribute__((ext_vector_type(8)));

#define F      65
#define NT     9            // 8 D-tiles of 32 cols + 1 S-tile
#define KS     5            // K padded 65 -> 80
#define RPB    256          // rows per block (8 waves x 32)
#define NCHUNK (NT*KS*64)   // 2880 16B chunks (46080 B)

__device__ __forceinline__ unsigned short f2bf(float f) {
  unsigned int u = __builtin_bit_cast(unsigned int, f);
  u += 0x7FFFu + ((u >> 16) & 1u);          // RNE
  return (unsigned short)(u >> 16);
}
__device__ __forceinline__ float fast_sigmoid(float x) {
  float e = __builtin_amdgcn_exp2f(-1.4426950408889634f * x);
  return __builtin_amdgcn_rcpf(1.0f + e);
}
template<int CTRL>
__device__ __forceinline__ float dpp_mov(float v) {
  return __builtin_bit_cast(float,
    __builtin_amdgcn_update_dpp(0, __builtin_bit_cast(int, v), CTRL, 0xF, 0xF, true));
}

// ---- prepass: fragment-ordered bf16 W blob in d_ws (unchanged, verified) ---
__global__ void prep_w(const float* __restrict__ W_S, const float* __restrict__ W_D,
                       unsigned short* __restrict__ wsb) {
  int b = blockIdx.x;              // t*KS+s
  int t = b / KS, s = b % KS;
  int l = threadIdx.x;
  int c = l & 31, g = l >> 5;
  short8 out;
#pragma unroll
  for (int j = 0; j < 8; ++j) {
    int k = 16 * s + 4 * g + (j & 3) + 8 * (j >> 2);
    int n = 32 * t + c;
    float v = 0.0f;
    if (k < F) {
      if (t < 8)      v = W_D[n * F + k];
      else if (c < 8) v = W_S[c * F + k];
    }
    out[j] = (short)f2bf(v);
  }
  reinterpret_cast<short8*>(wsb)[b * 64 + l] = out;
}

// ---- main fused kernel -----------------------------------------------------
__launch_bounds__(512, 4)
__global__ void mpuf_main(const float* __restrict__ phi,
                          const float* __restrict__ b_S,
                          const float* __restrict__ b_D,
                          const unsigned short* __restrict__ wsb,
                          float* __restrict__ out_ans,
                          float* __restrict__ out_rel) {
  __shared__ short8 ldsB[NCHUNK];          // 46080 B
  __shared__ float  soutv[RPB][8];         // 8192 B : f32 souts per row
  __shared__ float  rowrec[RPB][4];        // 4096 B : a67 per row

  const int tid  = threadIdx.x;
  const int wave = tid >> 6;
  const int l    = tid & 63;
  const int c    = l & 31;
  const int g    = l >> 5;
  const int wrow = wave * 32;
  const int rowg_base = blockIdx.x * RPB + wrow;

  const float* prow = phi + (size_t)(rowg_base + c) * F;

  // A loads: 8 x float4 (4B-aligned) + 1 scalar, issued up-front
  f32x4a f4[8];
#pragma unroll
  for (int s = 0; s < 4; ++s) {
    f4[2 * s]     = *reinterpret_cast<const f32x4a*>(prow + 16 * s + 4 * g);
    f4[2 * s + 1] = *reinterpret_cast<const f32x4a*>(prow + 16 * s + 4 * g + 8);
  }
  const float a64 = prow[64];

  // stage W blob -> LDS
  const short8* wsv = reinterpret_cast<const short8*>(wsb);
#pragma unroll
  for (int i = 0; i < 6; ++i) {
    int idx = tid + i * 512;
    if (idx < NCHUNK) ldsB[idx] = wsv[idx];
  }

  float bD[8];
#pragma unroll
  for (int t = 0; t < 8; ++t) bD[t] = b_D[32 * t + c];
  const float bS = b_S[c & 7];

  __syncthreads();

  // convert A to bf16 fragments (f4 regs die here)
  bf16x8 af[5];
#pragma unroll
  for (int s = 0; s < 4; ++s) {
    short8 ar;
#pragma unroll
    for (int j = 0; j < 4; ++j) {
      ar[j]     = (short)f2bf(f4[2 * s][j]);
      ar[j + 4] = (short)f2bf(f4[2 * s + 1][j]);
    }
    af[s] = __builtin_bit_cast(bf16x8, ar);
  }
  {
    short8 ar = {0, 0, 0, 0, 0, 0, 0, 0};
    if (g == 0) ar[0] = (short)f2bf(a64);
    af[4] = __builtin_bit_cast(bf16x8, ar);
  }

  // ---- S tile (tile 8) -----------------------------------------------------
  f32x16 accS = {};
#pragma unroll
  for (int s = 0; s < KS; ++s) {
    bf16x8 bf = __builtin_bit_cast(bf16x8, ldsB[(8 * KS + s) * 64 + l]);
    accS = __builtin_amdgcn_mfma_f32_32x32x16_bf16(af[s], bf, accS, 0, 0, 0);
  }

  // C layout (verified): col = lane&31, row = (r&3) + 8*(r>>2) + 4*(lane>>5)
  if (c < 8) {
#pragma unroll
    for (int r = 0; r < 16; ++r) {
      const int rl = (r & 3) + 8 * (r >> 2) + 4 * g;
      float sd = accS[r] + bS;
      out_rel[(size_t)(rowg_base + rl) * 8 + c] = fabsf(sd);
      soutv[wrow + rl][c] = fast_sigmoid(sd);   // f32, no pack
    }
  }
  // soutv/rowrec produced & consumed within the same wave -> no barrier;
  // compiler orders via lgkmcnt (same LDS arrays).

  // ---- per-row records: Msel pairs in regs, a67 in LDS ---------------------
  float Msel0[16], Msel1[16];
#pragma unroll
  for (int r = 0; r < 16; ++r) {
    const int rl = (r & 3) + 8 * (r >> 2) + 4 * g;
    const float* sp = &soutv[wrow + rl][0];
    f32x4 s0 = *reinterpret_cast<const f32x4*>(sp);
    f32x4 s1 = *reinterpret_cast<const f32x4*>(sp + 4);
    float Ml = 0.99999f;
    Ml *= ((c >> 0) & 1) ? s0[0] : 1.0f - s0[0];
    Ml *= ((c >> 1) & 1) ? s0[1] : 1.0f - s0[1];
    Ml *= ((c >> 2) & 1) ? s0[2] : 1.0f - s0[2];
    Ml *= ((c >> 3) & 1) ? s0[3] : 1.0f - s0[3];
    Ml *= ((c >> 4) & 1) ? s1[0] : 1.0f - s1[0];
    Msel1[r] = Ml * s1[1];                 // Ml * sv5
    Msel0[r] = Ml - Msel1[r];              // Ml * (1 - sv5)
    if (c == 0) {
      float ov6 = 1.0f - s1[2], ov7 = 1.0f - s1[3];
      f32x4 a67 = { ov6 * ov7, s1[2] * ov7, ov6 * s1[3], s1[2] * s1[3] };
      *reinterpret_cast<f32x4*>(&rowrec[wrow + rl][0]) = a67;
    }
  }

  float ansacc[16];
#pragma unroll
  for (int r = 0; r < 16; ++r) ansacc[r] = 0.0f;

  // ---- D tiles, t-outer: one 16-reg acc tile live at a time ----------------
#pragma unroll
  for (int t = 0; t < 8; ++t) {
    f32x16 acc = {};
#pragma unroll
    for (int s = 0; s < KS; ++s) {
      bf16x8 bf = __builtin_bit_cast(bf16x8, ldsB[(t * KS + s) * 64 + l]);
      acc = __builtin_amdgcn_mfma_f32_32x32x16_bf16(af[s], bf, acc, 0, 0, 0);
    }
#pragma unroll
    for (int r = 0; r < 16; ++r) {
      const int rl = (r & 3) + 8 * (r >> 2) + 4 * g;
      float dout = fast_sigmoid(acc[r] + bD[t]);
      float coef = ((t & 1) ? Msel1[r] : Msel0[r]) * rowrec[wrow + rl][t >> 1];
      ansacc[r] = fmaf(dout, coef, ansacc[r]);
    }
  }

  // ---- 32-lane row reduction + store ---------------------------------------
#pragma unroll
  for (int r = 0; r < 16; ++r) {
    const int rl = (r & 3) + 8 * (r >> 2) + 4 * g;
    float v = ansacc[r];
    v += dpp_mov<0xB1>(v);                 // xor1
    v += dpp_mov<0x4E>(v);                 // xor2
    v += dpp_mov<0x141>(v);                // xor4 (row_half_mirror)
    v += dpp_mov<0x140>(v);                // xor8 (row_mirror)
    v += __builtin_bit_cast(float,
          __builtin_amdgcn_ds_swizzle(__builtin_bit_cast(int, v), 0x401F)); // xor16
    if (c == 0) out_ans[rowg_base + rl] = v;
  }
}

extern "C" void kernel_launch(void* const* d_in, const int* in_sizes, int n_in,
                              void* d_out, int out_size, void* d_ws, size_t ws_size,
                              hipStream_t stream) {
  const float* phi = (const float*)d_in[0];
  const float* W_S = (const float*)d_in[1];
  const float* b_S = (const float*)d_in[2];
  const float* W_D = (const float*)d_in[3];
  const float* b_D = (const float*)d_in[4];
  const int rows = in_sizes[0] / F;        // 262144
  unsigned short* wsb = (unsigned short*)d_ws;
  float* out_ans = (float*)d_out;
  float* out_rel = out_ans + rows;
  hipLaunchKernelGGL(prep_w, dim3(NT * KS), dim3(64), 0, stream, W_S, W_D, wsb);
  hipLaunchKernelGGL(mpuf_main, dim3(rows / RPB), dim3(512), 0, stream,
                     phi, b_S, b_D, wsb, out_ans, out_rel);
}

// Round 3
// 477.729 us; speedup vs baseline: 1.0977x; 1.0977x over previous
//
#include <hip/hip_runtime.h>

typedef float  f32x16 __attribute__((ext_vector_type(16)));
typedef float  f32x4  __attribute__((ext_vector_type(4)));
typedef float  f32x4a __attribute__((ext_vector_type(4), aligned(4)));
typedef float  f32x2  __attribute__((ext_vector_type(2)));
typedef __bf16 bf16x8 __attribute__((ext_vector_type(8)));
typedef short  short8 __attribute__((ext_vector_type(8)));

#define F      65
#define KS     5            // K padded 65 -> 80
#define RPB    128          // rows per block (4 waves x 32)

__device__ __forceinline__ unsigned short f2bf(float f) {
  unsigned int u = __builtin_bit_cast(unsigned int, f);
  u += 0x7FFFu + ((u >> 16) & 1u);          // RNE
  return (unsigned short)(u >> 16);
}
__device__ __forceinline__ float fast_sigmoid(float x) {
  float e = __builtin_amdgcn_exp2f(-1.4426950408889634f * x);
  return __builtin_amdgcn_rcpf(1.0f + e);
}
template<int CTRL>
__device__ __forceinline__ float dpp_mov(float v) {
  return __builtin_bit_cast(float,
    __builtin_amdgcn_update_dpp(0, __builtin_bit_cast(int, v), CTRL, 0xF, 0xF, true));
}

// ---- prepass: fragment-ordered bf16 W blob in d_ws (verified R1) -----------
// chunk index = (t*KS+s)*64 + lane ; lane holds 8 bf16:
//   n = 32*t + (lane&31), k = 16*s + 4*(lane>>5) + (j&3) + 8*(j>>2)
__global__ void prep_w(const float* __restrict__ W_S, const float* __restrict__ W_D,
                       unsigned short* __restrict__ wsb) {
  int b = blockIdx.x;              // t*KS+s
  int t = b / KS, s = b % KS;
  int l = threadIdx.x;
  int c = l & 31, g = l >> 5;
  short8 out;
#pragma unroll
  for (int j = 0; j < 8; ++j) {
    int k = 16 * s + 4 * g + (j & 3) + 8 * (j >> 2);
    int n = 32 * t + c;
    float v = 0.0f;
    if (k < F) {
      if (t < 8)      v = W_D[n * F + k];
      else if (c < 8) v = W_S[c * F + k];
    }
    out[j] = (short)f2bf(v);
  }
  reinterpret_cast<short8*>(wsb)[b * 64 + l] = out;
}

// ---- main fused kernel -----------------------------------------------------
__launch_bounds__(256, 3)   // 3 blocks/CU -> 12 waves/CU, ~170-reg cap (no spill)
__global__ void mpuf_main(const float* __restrict__ phi,
                          const float* __restrict__ b_S,
                          const float* __restrict__ b_D,
                          const unsigned short* __restrict__ wsb,
                          float* __restrict__ out_ans,
                          float* __restrict__ out_rel) {
  __shared__ float soutv[RPB][8];          // 4 KB : f32 souts per row
  __shared__ float rowrec[RPB][8];         // 4 KB : per-row t-coefs w8[t]

  const int tid  = threadIdx.x;
  const int wave = tid >> 6;
  const int l    = tid & 63;
  const int c    = l & 31;
  const int g    = l >> 5;
  const int wrow = wave * 32;
  const int rowg_base = blockIdx.x * RPB + wrow;

  const float* prow = phi + (size_t)(rowg_base + c) * F;

  // A loads: 8 x dwordx4 (dword-aligned) + 1 scalar
  f32x4a f4[8];
#pragma unroll
  for (int s = 0; s < 4; ++s) {
    f4[2 * s]     = *reinterpret_cast<const f32x4a*>(prow + 16 * s + 4 * g);
    f4[2 * s + 1] = *reinterpret_cast<const f32x4a*>(prow + 16 * s + 4 * g + 8);
  }
  const float a64 = prow[64];

  float bD[8];
#pragma unroll
  for (int t = 0; t < 8; ++t) bD[t] = b_D[32 * t + c];
  const float bS = b_S[c & 7];

  // convert A to bf16 fragments
  bf16x8 af[5];
#pragma unroll
  for (int s = 0; s < 4; ++s) {
    short8 ar;
#pragma unroll
    for (int j = 0; j < 4; ++j) {
      ar[j]     = (short)f2bf(f4[2 * s][j]);
      ar[j + 4] = (short)f2bf(f4[2 * s + 1][j]);
    }
    af[s] = __builtin_bit_cast(bf16x8, ar);
  }
  {
    short8 ar = {0, 0, 0, 0, 0, 0, 0, 0};
    if (g == 0) ar[0] = (short)f2bf(a64);
    af[4] = __builtin_bit_cast(bf16x8, ar);
  }

  const short8* wsv = reinterpret_cast<const short8*>(wsb);  // L1/L2-resident

  // ---- S tile (tile 8): B direct from global -------------------------------
  f32x16 accS = {};
#pragma unroll
  for (int s = 0; s < KS; ++s) {
    bf16x8 bf = __builtin_bit_cast(bf16x8, wsv[(8 * KS + s) * 64 + l]);
    accS = __builtin_amdgcn_mfma_f32_32x32x16_bf16(af[s], bf, accS, 0, 0, 0);
  }

  // C layout (verified): col = lane&31, row = (r&3) + 8*(r>>2) + 4*(lane>>5)
  if (c < 8) {
#pragma unroll
    for (int r = 0; r < 16; ++r) {
      const int rl = (r & 3) + 8 * (r >> 2) + 4 * g;
      float sd = accS[r] + bS;
      out_rel[(size_t)(rowg_base + rl) * 8 + c] = fabsf(sd);
      soutv[wrow + rl][c] = fast_sigmoid(sd);
    }
  }
  // same-wave producer/consumer through LDS: compiler orders via lgkmcnt.

  // ---- per-row records: Ml in regs, w8[t] in LDS ---------------------------
  float Ml[16];
#pragma unroll
  for (int r = 0; r < 16; ++r) {
    const int rl = (r & 3) + 8 * (r >> 2) + 4 * g;
    f32x4 s0 = *reinterpret_cast<const f32x4*>(&soutv[wrow + rl][0]);
    f32x4 s1 = *reinterpret_cast<const f32x4*>(&soutv[wrow + rl][4]);
    float m = 0.99999f;
    m *= ((c >> 0) & 1) ? s0[0] : 1.0f - s0[0];
    m *= ((c >> 1) & 1) ? s0[1] : 1.0f - s0[1];
    m *= ((c >> 2) & 1) ? s0[2] : 1.0f - s0[2];
    m *= ((c >> 3) & 1) ? s0[3] : 1.0f - s0[3];
    m *= ((c >> 4) & 1) ? s1[0] : 1.0f - s1[0];
    Ml[r] = m;
    if (c == 0) {
      float s5 = s1[1], s6 = s1[2], s7 = s1[3];
      float o5 = 1.0f - s5, o6 = 1.0f - s6, o7 = 1.0f - s7;
      float a67[4] = { o6 * o7, s6 * o7, o6 * s7, s6 * s7 };
      f32x4 w0 = { o5 * a67[0], s5 * a67[0], o5 * a67[1], s5 * a67[1] };
      f32x4 w1 = { o5 * a67[2], s5 * a67[2], o5 * a67[3], s5 * a67[3] };
      *reinterpret_cast<f32x4*>(&rowrec[wrow + rl][0]) = w0;
      *reinterpret_cast<f32x4*>(&rowrec[wrow + rl][4]) = w1;
    }
  }

  float ansacc[16];
#pragma unroll
  for (int r = 0; r < 16; ++r) ansacc[r] = 0.0f;

  // ---- D tiles, pair-outer: two acc tiles live, B prefetched per pair ------
#pragma unroll
  for (int tp = 0; tp < 4; ++tp) {
    const int t0 = 2 * tp, t1 = t0 + 1;
    short8 braw0[KS], braw1[KS];
#pragma unroll
    for (int s = 0; s < KS; ++s) {
      braw0[s] = wsv[(t0 * KS + s) * 64 + l];
      braw1[s] = wsv[(t1 * KS + s) * 64 + l];
    }
    f32x16 acc0 = {}, acc1 = {};
#pragma unroll
    for (int s = 0; s < KS; ++s) {
      acc0 = __builtin_amdgcn_mfma_f32_32x32x16_bf16(
                 af[s], __builtin_bit_cast(bf16x8, braw0[s]), acc0, 0, 0, 0);
      acc1 = __builtin_amdgcn_mfma_f32_32x32x16_bf16(
                 af[s], __builtin_bit_cast(bf16x8, braw1[s]), acc1, 0, 0, 0);
    }
#pragma unroll
    for (int r = 0; r < 16; ++r) {
      const int rl = (r & 3) + 8 * (r >> 2) + 4 * g;
      f32x2 w = *reinterpret_cast<const f32x2*>(&rowrec[wrow + rl][t0]);
      float d0 = fast_sigmoid(acc0[r] + bD[t0]);
      float d1 = fast_sigmoid(acc1[r] + bD[t1]);
      ansacc[r] = fmaf(d0 * Ml[r], w[0], ansacc[r]);
      ansacc[r] = fmaf(d1 * Ml[r], w[1], ansacc[r]);
    }
  }

  // ---- 32-lane row reduction + store ---------------------------------------
#pragma unroll
  for (int r = 0; r < 16; ++r) {
    const int rl = (r & 3) + 8 * (r >> 2) + 4 * g;
    float v = ansacc[r];
    v += dpp_mov<0xB1>(v);                 // xor1
    v += dpp_mov<0x4E>(v);                 // xor2
    v += dpp_mov<0x141>(v);                // xor4 (row_half_mirror)
    v += dpp_mov<0x140>(v);                // xor8 (row_mirror)
    v += __builtin_bit_cast(float,
          __builtin_amdgcn_ds_swizzle(__builtin_bit_cast(int, v), 0x401F)); // xor16
    if (c == 0) out_ans[rowg_base + rl] = v;
  }
}

extern "C" void kernel_launch(void* const* d_in, const int* in_sizes, int n_in,
                              void* d_out, int out_size, void* d_ws, size_t ws_size,
                              hipStream_t stream) {
  const float* phi = (const float*)d_in[0];
  const float* W_S = (const float*)d_in[1];
  const float* b_S = (const float*)d_in[2];
  const float* W_D = (const float*)d_in[3];
  const float* b_D = (const float*)d_in[4];
  const int rows = in_sizes[0] / F;        // 262144
  unsigned short* wsb = (unsigned short*)d_ws;
  float* out_ans = (float*)d_out;
  float* out_rel = out_ans + rows;
  hipLaunchKernelGGL(prep_w, dim3(9 * KS), dim3(64), 0, stream, W_S, W_D, wsb);
  hipLaunchKernelGGL(mpuf_main, dim3(rows / RPB), dim3(256), 0, stream,
                     phi, b_S, b_D, wsb, out_ans, out_rel);
}

// Round 4
// 40.474 us; speedup vs baseline: 12.9567x; 11.8033x over previous
//
#include <hip/hip_runtime.h>

typedef float  f32x4  __attribute__((ext_vector_type(4)));
typedef float  f32x4a __attribute__((ext_vector_type(4), aligned(4)));
typedef float  f32x2  __attribute__((ext_vector_type(2)));
typedef __bf16 bf16x8 __attribute__((ext_vector_type(8)));
typedef short  short8 __attribute__((ext_vector_type(8)));

#define F      65
#define NTT    17           // 16 D-tiles of 16 cols + 1 S-tile
#define KS3    3            // K padded (65 real + 1 bias) -> 96, 3 ksteps of 32
#define RPB    128          // rows per block (8 waves x 16)
#define NCHUNK (NTT*KS3*64) // 3264 16B chunks (52224 B)

__device__ __forceinline__ unsigned short f2bf(float f) {
  unsigned int u = __builtin_bit_cast(unsigned int, f);
  u += 0x7FFFu + ((u >> 16) & 1u);          // RNE
  return (unsigned short)(u >> 16);
}
__device__ __forceinline__ float fast_sigmoid(float x) {
  float e = __builtin_amdgcn_exp2f(-1.4426950408889634f * x);
  return __builtin_amdgcn_rcpf(1.0f + e);
}
template<int CTRL>
__device__ __forceinline__ float dpp_mov(float v) {
  return __builtin_bit_cast(float,
    __builtin_amdgcn_update_dpp(0, __builtin_bit_cast(int, v), CTRL, 0xF, 0xF, true));
}

// ---- prepass: fragment-ordered bf16 W blob (16x16 layout, bias folded) -----
// chunk = (t*3+s)*64 + lane ; lane holds 8 bf16 of B:
//   col n = 16*t + (lane&15), k = 32*s + 8*(lane>>4) + j   (k==65 is bias row)
__global__ void prep_w(const float* __restrict__ W_S, const float* __restrict__ b_S,
                       const float* __restrict__ W_D, const float* __restrict__ b_D,
                       unsigned short* __restrict__ wsb) {
  int b = blockIdx.x;              // 0..50 = t*3+s
  int t = b / 3, s = b % 3;
  int l = threadIdx.x;
  int c = l & 15, q = l >> 4;
  short8 out;
#pragma unroll
  for (int j = 0; j < 8; ++j) {
    int k = 32 * s + 8 * q + j;
    float v = 0.0f;
    if (t < 16) {
      int n = 16 * t + c;
      if (k < F)       v = W_D[n * F + k];
      else if (k == F) v = b_D[n];
    } else if (c < 8) {
      if (k < F)       v = W_S[c * F + k];
      else if (k == F) v = b_S[c];
    }
    out[j] = (short)f2bf(v);
  }
  reinterpret_cast<short8*>(wsb)[b * 64 + l] = out;
}

// ---- main fused kernel -----------------------------------------------------
__launch_bounds__(512, 4)   // 4 waves/EU -> unified reg cap 128; live set ~90
__global__ void mpuf_main(const float* __restrict__ phi,
                          const unsigned short* __restrict__ wsb,
                          float* __restrict__ out_ans,
                          float* __restrict__ out_rel) {
  __shared__ short8 ldsB[NCHUNK];          // 52224 B
  __shared__ float  soutv[RPB][10];        // 5120 B (pad 10: bank-shift 8/row-quad)
  __shared__ float  rowrec[RPB][18];       // 9216 B (pad 18: bank-shift 8/row-quad)

  const int tid  = threadIdx.x;
  const int wave = tid >> 6;
  const int l    = tid & 63;
  const int c    = l & 15;                 // A-row in wave-tile / B-col in tile
  const int q    = l >> 4;                 // k-group
  const int wrow = wave * 16;
  const int brow = blockIdx.x * RPB;       // block's first global row

  const float* prow = phi + (size_t)(brow + wrow + c) * F;

  // A loads: 4 x dwordx4 (k = 32s + 8q + j contiguous) + phi[64]
  f32x4a f4[4];
#pragma unroll
  for (int s = 0; s < 2; ++s) {
    f4[2 * s]     = *reinterpret_cast<const f32x4a*>(prow + 32 * s + 8 * q);
    f4[2 * s + 1] = *reinterpret_cast<const f32x4a*>(prow + 32 * s + 8 * q + 4);
  }
  const float a64 = prow[64];

  // stage W blob -> LDS (3264 chunks / 512 threads)
  const short8* wsv = reinterpret_cast<const short8*>(wsb);
#pragma unroll
  for (int i = 0; i < 7; ++i) {
    int idx = tid + i * 512;
    if (idx < NCHUNK) ldsB[idx] = wsv[idx];
  }

  // convert A to bf16 fragments
  bf16x8 af[3];
#pragma unroll
  for (int s = 0; s < 2; ++s) {
    short8 ar;
#pragma unroll
    for (int j = 0; j < 4; ++j) {
      ar[j]     = (short)f2bf(f4[2 * s][j]);
      ar[j + 4] = (short)f2bf(f4[2 * s + 1][j]);
    }
    af[s] = __builtin_bit_cast(bf16x8, ar);
  }
  {
    short8 ar = {0, 0, 0, 0, 0, 0, 0, 0};
    if (q == 0) {
      ar[0] = (short)f2bf(a64);            // k=64: last phi element
      ar[1] = (short)0x3F80;               // k=65: 1.0 -> bias row
    }
    af[2] = __builtin_bit_cast(bf16x8, ar);
  }

  __syncthreads();

  // ---- S tile (tile 16): Sdelta incl. bias ---------------------------------
  f32x4 accS = {};
#pragma unroll
  for (int s = 0; s < KS3; ++s)
    accS = __builtin_amdgcn_mfma_f32_16x16x32_bf16(
               af[s], __builtin_bit_cast(bf16x8, ldsB[(16 * KS3 + s) * 64 + l]),
               accS, 0, 0, 0);

  // C layout 16x16: col = lane&15, row = (lane>>4)*4 + r
  if (c < 8) {
#pragma unroll
    for (int r = 0; r < 4; ++r) {
      const int R = wrow + q * 4 + r;
      float sd = accS[r];
      out_rel[(size_t)(brow + R) * 8 + c] = fabsf(sd);
      soutv[R][c] = fast_sigmoid(sd);
    }
  }
  // same-wave producer/consumer through LDS (lgkmcnt-ordered, R1-verified)

  // ---- per-row: Ml (bits 0-3 of d = c) in regs; Mt (bits 4-7 = t) in LDS ---
  float Ml[4];
#pragma unroll
  for (int r = 0; r < 4; ++r) {
    const int R = wrow + q * 4 + r;
    f32x2 p01 = *reinterpret_cast<const f32x2*>(&soutv[R][0]);
    f32x2 p23 = *reinterpret_cast<const f32x2*>(&soutv[R][2]);
    f32x2 p45 = *reinterpret_cast<const f32x2*>(&soutv[R][4]);
    f32x2 p67 = *reinterpret_cast<const f32x2*>(&soutv[R][6]);
    float m = 0.99999f;
    m *= (c & 1) ? p01[0] : 1.0f - p01[0];
    m *= (c & 2) ? p01[1] : 1.0f - p01[1];
    m *= (c & 4) ? p23[0] : 1.0f - p23[0];
    m *= (c & 8) ? p23[1] : 1.0f - p23[1];
    Ml[r] = m;
    float mt = (c & 1) ? p45[0] : 1.0f - p45[0];
    mt *= (c & 2) ? p45[1] : 1.0f - p45[1];
    mt *= (c & 4) ? p67[0] : 1.0f - p67[0];
    mt *= (c & 8) ? p67[1] : 1.0f - p67[1];
    rowrec[R][c] = mt;                     // Mt for tile t = c
  }

  float ansacc[4] = {0.0f, 0.0f, 0.0f, 0.0f};

  // ---- D tiles, pair-outer: only 8 acc regs live ---------------------------
#pragma unroll 1
  for (int tp = 0; tp < 8; ++tp) {
    const int t0 = 2 * tp, t1 = t0 + 1;
    f32x4 A0 = {}, A1 = {};
#pragma unroll
    for (int s = 0; s < KS3; ++s)
      A0 = __builtin_amdgcn_mfma_f32_16x16x32_bf16(
               af[s], __builtin_bit_cast(bf16x8, ldsB[(t0 * KS3 + s) * 64 + l]),
               A0, 0, 0, 0);
#pragma unroll
    for (int s = 0; s < KS3; ++s)
      A1 = __builtin_amdgcn_mfma_f32_16x16x32_bf16(
               af[s], __builtin_bit_cast(bf16x8, ldsB[(t1 * KS3 + s) * 64 + l]),
               A1, 0, 0, 0);
#pragma unroll
    for (int r = 0; r < 4; ++r) {
      const int R = wrow + q * 4 + r;
      f32x2 w = *reinterpret_cast<const f32x2*>(&rowrec[R][t0]);
      float d0 = fast_sigmoid(A0[r]);      // bias folded into acc
      float d1 = fast_sigmoid(A1[r]);
      ansacc[r] = fmaf(d0, Ml[r] * w[0], ansacc[r]);
      ansacc[r] = fmaf(d1, Ml[r] * w[1], ansacc[r]);
    }
  }

  // ---- 16-lane row reduction (4 DPP xors) + vectorized store ---------------
#pragma unroll
  for (int r = 0; r < 4; ++r) {
    float v = ansacc[r];
    v += dpp_mov<0xB1>(v);                 // xor1 (quad_perm)
    v += dpp_mov<0x4E>(v);                 // xor2 (quad_perm)
    v += dpp_mov<0x141>(v);                // row_half_mirror (pairs quads 0-1,2-3)
    v += dpp_mov<0x140>(v);                // row_mirror (pairs halves)
    ansacc[r] = v;                         // all 16 lanes hold row sum
  }
  if (c == 0) {
    f32x4 o = { ansacc[0], ansacc[1], ansacc[2], ansacc[3] };
    *reinterpret_cast<f32x4*>(&out_ans[brow + wrow + q * 4]) = o;
  }
}

extern "C" void kernel_launch(void* const* d_in, const int* in_sizes, int n_in,
                              void* d_out, int out_size, void* d_ws, size_t ws_size,
                              hipStream_t stream) {
  const float* phi = (const float*)d_in[0];
  const float* W_S = (const float*)d_in[1];
  const float* b_S = (const float*)d_in[2];
  const float* W_D = (const float*)d_in[3];
  const float* b_D = (const float*)d_in[4];
  const int rows = in_sizes[0] / F;        // 262144
  unsigned short* wsb = (unsigned short*)d_ws;   // 52224 B used
  float* out_ans = (float*)d_out;
  float* out_rel = out_ans + rows;
  hipLaunchKernelGGL(prep_w, dim3(NTT * KS3), dim3(64), 0, stream,
                     W_S, b_S, W_D, b_D, wsb);
  hipLaunchKernelGGL(mpuf_main, dim3(rows / RPB), dim3(512), 0, stream,
                     phi, wsb, out_ans, out_rel);
}